// Round 20
// baseline (271.434 us; speedup 1.0000x reference)
//
#include <hip/hip_runtime.h>
#include <stdint.h>
#include <stddef.h>

// MHA + residual + LayerNorm. Inputs f32, outputs f32 (out0 + attn), internals bf16.
// B=2, L=T=2048, H=16, DK=DV=64, DM=1024   MI355X (gfx950)
// R20 (from R19 anchor 262.8us): base-2 softmax folding.
//   q pre-scaled by 0.125*log2(e); phase1 uses exp2f(st-C); phase2 folds the
//   row normalization INTO the exponent: p = exp2f(st + c2), c2 = -log2(ls)-C.
//   Score-element VALU: phase2 4->2 insts, phase1 4->3. Identity math.

typedef __attribute__((ext_vector_type(8))) short short8;
typedef __attribute__((ext_vector_type(4))) short short4v;
typedef __attribute__((ext_vector_type(4))) float f32x4;

#define MFMA16 __builtin_amdgcn_mfma_f32_16x16x32_bf16
#define SM_C 17.312340490667562f   // 12 * log2(e)

__device__ __forceinline__ float bf2f(short s) {
    union { unsigned u; float f; } c; c.u = ((unsigned)(unsigned short)s) << 16; return c.f;
}
__device__ __forceinline__ unsigned short f2bf(float x) {
    union { float f; unsigned u; } c; c.f = x;
    unsigned r = (c.u + 0x7FFFu + ((c.u >> 16) & 1u)) >> 16;
    return (unsigned short)r;
}
__device__ __forceinline__ unsigned pk2(float a, float b) {
    return (unsigned)f2bf(a) | ((unsigned)f2bf(b) << 16);
}
__device__ __forceinline__ short8 ld8f(const float* p) {   // 8 f32 -> 8 bf16
    const f32x4 x = *(const f32x4*)p, y = *(const f32x4*)(p + 4);
    short8 r;
    r[0] = (short)f2bf(x[0]); r[1] = (short)f2bf(x[1]);
    r[2] = (short)f2bf(x[2]); r[3] = (short)f2bf(x[3]);
    r[4] = (short)f2bf(y[0]); r[5] = (short)f2bf(y[1]);
    r[6] = (short)f2bf(y[2]); r[7] = (short)f2bf(y[3]);
    return r;
}
// direct global->LDS 16B load; lands at lds_base + lane*16 (wave-uniform base)
__device__ __forceinline__ void gll16(const short* g, short* l) {
    __builtin_amdgcn_global_load_lds(
        (const __attribute__((address_space(1))) unsigned int*)g,
        (__attribute__((address_space(3))) unsigned int*)l,
        16, 0, 0);
}

// ---------------------------------------------------------------------------
// f32 -> bf16 bulk convert. blockIdx.y selects tensor. (unchanged)
// ---------------------------------------------------------------------------
__global__ __launch_bounds__(256)
void cvt_k(const float* __restrict__ s0, const float* __restrict__ s1,
           const float* __restrict__ s2, const float* __restrict__ s3,
           const float* __restrict__ s4, const float* __restrict__ s5,
           const float* __restrict__ s6,
           short* __restrict__ d0, short* __restrict__ d1, short* __restrict__ d2,
           short* __restrict__ d3, short* __restrict__ d4, short* __restrict__ d5,
           short* __restrict__ d6)
{
    const int t = blockIdx.y;
    const float* s; short* d; int n;
    switch (t) {
        case 0: s = s0; d = d0; n = 4194304; break;
        case 1: s = s1; d = d1; n = 4194304; break;
        case 2: s = s2; d = d2; n = 4194304; break;
        case 3: s = s3; d = d3; n = 1048576; break;
        case 4: s = s4; d = d4; n = 1048576; break;
        case 5: s = s5; d = d5; n = 1048576; break;
        default: s = s6; d = d6; n = 1048576; break;
    }
    const int idx = (blockIdx.x * 256 + threadIdx.x) * 8;
    if (idx < n) *(short8*)(d + idx) = ld8f(s + idx);
}

// ---------------------------------------------------------------------------
// m97-style GEMM with LDS-transpose coalesced epilogue.
// OP==0: BM=128, projections (z: 0=q [scaled 0.125*log2e], 1=k, 2=vT).
// OP==1: BM=64, fc + f32 resid -> bf16 row-major; grid (64,8)=512 blocks.
// ---------------------------------------------------------------------------
template<int OP>
__global__ __launch_bounds__(256)
void gemm_k(const short* __restrict__ A0, const short* __restrict__ A1, const short* __restrict__ A2,
            const short* __restrict__ W0, const short* __restrict__ W1, const short* __restrict__ W2,
            const float* __restrict__ bz0, const float* __restrict__ bz1, const float* __restrict__ bz2,
            short* __restrict__ D0, short* __restrict__ D1, short* __restrict__ D2,
            const float* __restrict__ resid, short* __restrict__ yout)
{
    constexpr int BM  = (OP == 1) ? 64 : 128;
    constexpr int ASH = BM * 32;                 // A-tile shorts
    constexpr int MTN = (OP == 1) ? 2 : 4;
    __shared__ short lds[2][ASH + 4096];         // A @0, W @ASH
    const int tid = threadIdx.x;
    const int lane = tid & 63, w = tid >> 6;
    const int rl = lane & 15, q = lane >> 4;
    const int m0 = blockIdx.x * BM, n0 = blockIdx.y * 128;
    const int wrow = (OP == 1) ? ((w >> 1) * 32) : ((w >> 1) * 64);
    const int wcol = (w & 1) * 64;

    const short *Ag, *Wg; const float* bias; short* dst; int zm;
    float oscale = 1.f;
    if (OP == 0) {
        const int z = blockIdx.z;
        Ag  = (z == 0) ? A0 : (z == 1) ? A1 : A2;
        Wg  = (z == 0) ? W0 : (z == 1) ? W1 : W2;
        bias= (z == 0) ? bz0 : (z == 1) ? bz1 : bz2;
        dst = (z == 0) ? D0 : (z == 1) ? D1 : D2;
        zm  = (z == 2) ? 1 : 0;
        if (z == 0) oscale = 0.18033688011112042f;   // 0.125 * log2(e)
    } else {
        Ag = A0; Wg = W0; bias = bz0; dst = yout; zm = 2;
    }

    f32x4 acc[MTN][4];
    #pragma unroll
    for (int a = 0; a < MTN; ++a)
      #pragma unroll
      for (int b = 0; b < 4; ++b) acc[a][b] = (f32x4){0.f, 0.f, 0.f, 0.f};

    const int lr4 = lane >> 2;
    const int sc  = (lane & 3) * 8;

    auto stage = [&](int buf, int kt) {
        if (OP == 0) {
            gll16(Ag + (size_t)(m0 + (w*2+0)*16 + lr4) * 1024 + kt + sc, &lds[buf][(w*2+0)*512]);
            gll16(Ag + (size_t)(m0 + (w*2+1)*16 + lr4) * 1024 + kt + sc, &lds[buf][(w*2+1)*512]);
        } else {
            gll16(Ag + (size_t)(m0 + w*16 + lr4) * 1024 + kt + sc, &lds[buf][w*512]);
        }
        gll16(Wg + (size_t)(n0 + (w*2+0)*16 + lr4) * 1024 + kt + sc, &lds[buf][ASH+(w*2+0)*512]);
        gll16(Wg + (size_t)(n0 + (w*2+1)*16 + lr4) * 1024 + kt + sc, &lds[buf][ASH+(w*2+1)*512]);
    };

    stage(0, 0);
    __syncthreads();
    int cur = 0;
    for (int kt = 0; kt < 1024; kt += 32) {
        if (kt + 32 < 1024) { stage(cur ^ 1, kt + 32); }
        short8 af[MTN], bfv[4];
        #pragma unroll
        for (int mt = 0; mt < MTN; ++mt)
            af[mt] = *(const short8*)&lds[cur][(wrow + mt * 16 + rl) * 32 + q * 8];
        #pragma unroll
        for (int nt = 0; nt < 4; ++nt)
            bfv[nt] = *(const short8*)&lds[cur][ASH + (wcol + nt * 16 + rl) * 32 + q * 8];
        #pragma unroll
        for (int mt = 0; mt < MTN; ++mt)
          #pragma unroll
          for (int nt = 0; nt < 4; ++nt)
            acc[mt][nt] = MFMA16(af[mt], bfv[nt], acc[mt][nt], 0, 0, 0);
        __syncthreads();
        cur ^= 1;
    }

    float biasv[4];
    #pragma unroll
    for (int nt = 0; nt < 4; ++nt) biasv[nt] = bias[n0 + wcol + nt * 16 + rl];

    short* ldsF = &lds[0][0];          // epilogue scratch (64 x 136 shorts)

    if (zm == 0) {
        #pragma unroll
        for (int pass = 0; pass < 2; ++pass) {
            if ((w >> 1) == pass) {
                #pragma unroll
                for (int mt = 0; mt < 4; ++mt)
                  #pragma unroll
                  for (int nt = 0; nt < 4; ++nt) {
                    const int col = wcol + nt * 16 + rl;
                    #pragma unroll
                    for (int i = 0; i < 4; ++i)
                        ldsF[(mt * 16 + q * 4 + i) * 136 + col] =
                            (short)f2bf((acc[mt][nt][i] + biasv[nt]) * oscale);
                  }
            }
            __syncthreads();
            {
                const int hrun = tid >> 7, idx = tid & 127;
                const int lr = idx >> 1, ch = idx & 1;
                const int gm = m0 + pass * 64 + lr;
                const int bb = gm >> 11, ll = gm & 2047;
                const int h = (n0 + hrun * 64) >> 6;
                short* dstp = dst + (((size_t)(bb * 16 + h) * 2048) + ll) * 64 + ch * 32;
                const short* srcp = &ldsF[lr * 136 + hrun * 64 + ch * 32];
                #pragma unroll
                for (int c = 0; c < 4; ++c)
                    *(short8*)(dstp + c * 8) = *(const short8*)(srcp + c * 8);
            }
            __syncthreads();
        }
    } else if (zm == 1) {
        const int bb = m0 >> 11, t0 = m0 & 2047;
        #pragma unroll
        for (int pass = 0; pass < 2; ++pass) {
            if ((w & 1) == pass) {
                #pragma unroll
                for (int nt = 0; nt < 4; ++nt) {
                    const int lcol = nt * 16 + rl;
                    #pragma unroll
                    for (int mt = 0; mt < 4; ++mt) {
                        const int mloc = wrow + mt * 16 + q * 4;
                        const unsigned lo = pk2(acc[mt][nt][0] + biasv[nt],
                                                acc[mt][nt][1] + biasv[nt]);
                        const unsigned hi = pk2(acc[mt][nt][2] + biasv[nt],
                                                acc[mt][nt][3] + biasv[nt]);
                        *(unsigned long long*)&ldsF[lcol * 136 + mloc] =
                            (unsigned long long)lo | ((unsigned long long)hi << 32);
                    }
                }
            }
            __syncthreads();
            {
                const int lcol = tid >> 2, mch = tid & 3;
                const int gn = n0 + pass * 64 + lcol;
                const int h = gn >> 6, dv = gn & 63;
                short* dstp = dst + ((size_t)(bb * 16 + h) * 64 + dv) * 2048 + t0 + mch * 32;
                const short* srcp = &ldsF[lcol * 136 + mch * 32];
                #pragma unroll
                for (int c = 0; c < 4; ++c)
                    *(short8*)(dstp + c * 8) = *(const short8*)(srcp + c * 8);
            }
            __syncthreads();
        }
    } else {
        // fc, BM=64: single pass; all 4 waves fill 64x128 ldsF then store.
        #pragma unroll
        for (int mt = 0; mt < MTN; ++mt)
          #pragma unroll
          for (int nt = 0; nt < 4; ++nt) {
            const int col = wcol + nt * 16 + rl;
            #pragma unroll
            for (int i = 0; i < 4; ++i)
                ldsF[(wrow + mt * 16 + q * 4 + i) * 136 + col] =
                    (short)f2bf(acc[mt][nt][i] + biasv[nt]);
          }
        __syncthreads();
        {
            const int lr = tid >> 2, ch = tid & 3;
            const int gm = m0 + lr;
            const float* rp = resid + (size_t)gm * 1024 + n0 + ch * 32;
            short* dstp = dst + (size_t)gm * 1024 + n0 + ch * 32;
            const short* srcp = &ldsF[lr * 136 + ch * 32];
            #pragma unroll
            for (int c = 0; c < 4; ++c) {
                const short8 v = *(const short8*)(srcp + c * 8);
                const f32x4 r0 = *(const f32x4*)(rp + c * 8);
                const f32x4 r1 = *(const f32x4*)(rp + c * 8 + 4);
                short8 o;
                #pragma unroll
                for (int j = 0; j < 4; ++j) {
                    o[j]     = (short)f2bf(bf2f(v[j])     + r0[j]);
                    o[4 + j] = (short)f2bf(bf2f(v[4 + j]) + r1[j]);
                }
                *(short8*)(dstp + c * 8) = o;
            }
        }
    }
}

// ---------------------------------------------------------------------------
// XCD swizzle for the 512-block attention grid.
// ---------------------------------------------------------------------------
__device__ __forceinline__ void attn_swz(int j, int& rb, int& bh) {
    const int xcd = j & 7, k2 = j >> 3;
    rb = k2 & 15;
    bh = (xcd << 2) | (k2 >> 4);
}

// ---------------------------------------------------------------------------
// FUSED attention, 8 waves (512 thr), 128 q-rows per block. Base-2 softmax:
// q pre-scaled by 0.125*log2e => p = exp2(st + c2), c2 = -log2(ls) - C.
// ---------------------------------------------------------------------------
__global__ __launch_bounds__(512)
void attn_fused(const short* __restrict__ qh, const short* __restrict__ kh,
                const short* __restrict__ vhT,
                float* __restrict__ attn, short* __restrict__ Obf)
{
    __shared__ short ldsK[128 * 72];
    __shared__ short ldsV[64 * 136];
    __shared__ short ldsP[8][16 * 72];    // per-wave P half-tile: 16 r x 64 t (+pad)
    const int tid = threadIdx.x, lane = tid & 63, w = tid >> 6;   // w 0..7
    const int rl = lane & 15, q = lane >> 4;
    int rb, bh; attn_swz(blockIdx.x, rb, bh);
    const int r = rb * 128 + w * 16 + rl;
    const int b = bh >> 4, h = bh & 15;

    const size_t qoff = ((size_t)bh * 2048 + r) * 64;
    const short8 bq0 = *(const short8*)(qh + qoff + q * 8);
    const short8 bq1 = *(const short8*)(qh + qoff + 32 + q * 8);

    const size_t kbase = (size_t)bh * 2048 * 64;
    const size_t vbase = (size_t)bh * 64 * 2048;
    const int srow = tid >> 2, soff = (tid & 3) * 16;   // K staging: 128 rows, 32B/thr
    const int vrow = tid >> 3, voff = (tid & 7) * 16;   // V staging: 64 rows, 32B/thr
    const size_t abaseW = (((size_t)b * 2048 + rb * 128 + w * 16) * 16 + h) * 2048;

    // ---------------- phase 1: row sum of exp2(st - C) ----------------
    float ls0 = 0.f, ls1 = 0.f, ls2 = 0.f, ls3 = 0.f;
    short8 kst[2], vst[2];
    {
        const short* src = kh + kbase + (size_t)srow * 64 + soff;
        kst[0] = *(const short8*)src;
        kst[1] = *(const short8*)(src + 8);
    }
    for (int it = 0; it < 16; ++it) {
        __syncthreads();
        *(short8*)&ldsK[srow * 72 + soff]     = kst[0];
        *(short8*)&ldsK[srow * 72 + soff + 8] = kst[1];
        __syncthreads();
        if (it < 15) {
            const short* src = kh + kbase + (size_t)(((it + 1) << 7) + srow) * 64 + soff;
            kst[0] = *(const short8*)src;
            kst[1] = *(const short8*)(src + 8);
        }
        #pragma unroll
        for (int tt = 0; tt < 8; ++tt) {
            const short* kr = &ldsK[(tt * 16 + rl) * 72];
            const short8 ak0 = *(const short8*)(kr + q * 8);
            const short8 ak1 = *(const short8*)(kr + 32 + q * 8);
            f32x4 st = MFMA16(ak0, bq0, (f32x4){0.f, 0.f, 0.f, 0.f}, 0, 0, 0);
            st = MFMA16(ak1, bq1, st, 0, 0, 0);
            ls0 += exp2f(st[0] - SM_C);
            ls1 += exp2f(st[1] - SM_C);
            ls2 += exp2f(st[2] - SM_C);
            ls3 += exp2f(st[3] - SM_C);
        }
    }
    float ls = (ls0 + ls1) + (ls2 + ls3);
    ls += __shfl_xor(ls, 16);
    ls += __shfl_xor(ls, 32);
    const float c2 = -log2f(ls) - SM_C;   // p = exp2(st + c2) is fully normalized

    // ---------------- phase 2: P write + PV ----------------
    f32x4 acc[4];
    #pragma unroll
    for (int dt = 0; dt < 4; ++dt) acc[dt] = (f32x4){0.f, 0.f, 0.f, 0.f};

    {
        const short* ks = kh + kbase + (size_t)srow * 64 + soff;
        const short* vs = vhT + vbase + (size_t)vrow * 2048 + voff;
        kst[0] = *(const short8*)ks;  kst[1] = *(const short8*)(ks + 8);
        vst[0] = *(const short8*)vs;  vst[1] = *(const short8*)(vs + 8);
    }
    for (int it = 0; it < 16; ++it) {
        const int t0 = it << 7;
        __syncthreads();
        *(short8*)&ldsK[srow * 72 + soff]      = kst[0];
        *(short8*)&ldsK[srow * 72 + soff + 8]  = kst[1];
        *(short8*)&ldsV[vrow * 136 + voff]     = vst[0];
        *(short8*)&ldsV[vrow * 136 + voff + 8] = vst[1];
        __syncthreads();
        if (it < 15) {
            const short* ks = kh + kbase + (size_t)(t0 + 128 + srow) * 64 + soff;
            const short* vs = vhT + vbase + (size_t)vrow * 2048 + t0 + 128 + voff;
            kst[0] = *(const short8*)ks;  kst[1] = *(const short8*)(ks + 8);
            vst[0] = *(const short8*)vs;  vst[1] = *(const short8*)(vs + 8);
        }
        #pragma unroll
        for (int hh = 0; hh < 4; ++hh) {
            float pv[8];
            #pragma unroll
            for (int sub = 0; sub < 2; ++sub) {
                const int tt = hh * 2 + sub;
                const short* kr = &ldsK[(tt * 16 + rl) * 72];
                const short8 ak0 = *(const short8*)(kr + q * 8);
                const short8 ak1 = *(const short8*)(kr + 32 + q * 8);
                f32x4 st = MFMA16(ak0, bq0, (f32x4){0.f, 0.f, 0.f, 0.f}, 0, 0, 0);
                st = MFMA16(ak1, bq1, st, 0, 0, 0);
                #pragma unroll
                for (int i = 0; i < 4; ++i)
                    pv[sub * 4 + i] = exp2f(st[i] + c2);
            }
            short8 pb;
            #pragma unroll
            for (int j = 0; j < 8; ++j) pb[j] = (short)f2bf(pv[j]);
            {
                const int lc = (hh & 1) * 32;
                short4v plo, phi;
                plo[0] = pb[0]; plo[1] = pb[1]; plo[2] = pb[2]; plo[3] = pb[3];
                phi[0] = pb[4]; phi[1] = pb[5]; phi[2] = pb[6]; phi[3] = pb[7];
                *(short4v*)&ldsP[w][rl * 72 + lc + q * 4] = plo;
                *(short4v*)&ldsP[w][rl * 72 + lc + 16 + q * 4] = phi;
            }
            #pragma unroll
            for (int dt = 0; dt < 4; ++dt) {
                const short* vr = &ldsV[(dt * 16 + rl) * 136 + hh * 32];
                const short4v vlo = *(const short4v*)(vr + q * 4);
                const short4v vhi = *(const short4v*)(vr + 16 + q * 4);
                short8 va;
                va[0] = vlo[0]; va[1] = vlo[1]; va[2] = vlo[2]; va[3] = vlo[3];
                va[4] = vhi[0]; va[5] = vhi[1]; va[6] = vhi[2]; va[7] = vhi[3];
                acc[dt] = MFMA16(va, pb, acc[dt], 0, 0, 0);
            }
            if ((hh & 1) && attn != nullptr) {
                const int hcol = hh >> 1;
                const int c8 = (lane & 7) * 8;
                #pragma unroll
                for (int pass = 0; pass < 2; ++pass) {
                    const int rloc = pass * 8 + (lane >> 3);
                    const short8 p8 = *(const short8*)&ldsP[w][rloc * 72 + c8];
                    float* dstp = attn + abaseW + (size_t)rloc * 32768 + t0 + hcol * 64 + c8;
                    f32x4 o0, o1;
                    #pragma unroll
                    for (int j = 0; j < 4; ++j) {
                        o0[j] = bf2f(p8[j]);
                        o1[j] = bf2f(p8[4 + j]);
                    }
                    *(f32x4*)dstp = o0;
                    *(f32x4*)(dstp + 4) = o1;
                }
            }
        }
    }

    #pragma unroll
    for (int dt = 0; dt < 4; ++dt) {
        const int dv0 = dt * 16 + q * 4;
        const unsigned lo = pk2(acc[dt][0], acc[dt][1]);
        const unsigned hi = pk2(acc[dt][2], acc[dt][3]);
        const size_t oidx = ((size_t)b * 2048 + r) * 1024 + h * 64 + dv0;
        *(unsigned long long*)&Obf[oidx] =
            (unsigned long long)lo | ((unsigned long long)hi << 32);
    }
}

// ---------------------------------------------------------------------------
// Rowwise LayerNorm. ybf bf16 in, out f32. (unchanged)
// ---------------------------------------------------------------------------
__global__ __launch_bounds__(256)
void ln_k(const short* __restrict__ ybf, const float* __restrict__ gamma,
          const float* __restrict__ beta, float* __restrict__ out)
{
    const int tid = threadIdx.x, lane = tid & 63, w = tid >> 6;
    const int row = blockIdx.x * 4 + w;
    const short* yr = ybf + (size_t)row * 1024 + lane * 16;
    const short8 v0 = *(const short8*)(yr);
    const short8 v1 = *(const short8*)(yr + 8);
    float x[16];
    #pragma unroll
    for (int j = 0; j < 8; ++j) { x[j] = bf2f(v0[j]); x[8 + j] = bf2f(v1[j]); }
    float s = 0.f, s2 = 0.f;
    #pragma unroll
    for (int j = 0; j < 16; ++j) { s += x[j]; s2 += x[j] * x[j]; }
    #pragma unroll
    for (int off = 1; off < 64; off <<= 1) {
        s  += __shfl_xor(s, off);
        s2 += __shfl_xor(s2, off);
    }
    const float mean = s * (1.f / 1024.f);
    const float var  = s2 * (1.f / 1024.f) - mean * mean;
    const float rs   = rsqrtf(var + 1e-5f);
    float* orow = out + (size_t)row * 1024 + lane * 16;
    #pragma unroll
    for (int j4 = 0; j4 < 4; ++j4) {
        f32x4 o;
        #pragma unroll
        for (int e = 0; e < 4; ++e) {
            const int c = lane * 16 + j4 * 4 + e;
            o[e] = (x[j4 * 4 + e] - mean) * rs * gamma[c] + beta[c];
        }
        *(f32x4*)(orow + j4 * 4) = o;
    }
}

// ---------------------------------------------------------------------------
extern "C" void kernel_launch(void* const* d_in, const int* in_sizes, int n_in,
                              void* d_out, int out_size, void* d_ws, size_t ws_size,
                              hipStream_t stream)
{
    (void)in_sizes; (void)n_in;
    const float* qin  = (const float*)d_in[0];
    const float* kin  = (const float*)d_in[1];
    const float* vin  = (const float*)d_in[2];
    const float* wq   = (const float*)d_in[3];
    const float* b_q  = (const float*)d_in[4];
    const float* wk   = (const float*)d_in[5];
    const float* b_k  = (const float*)d_in[6];
    const float* wv   = (const float*)d_in[7];
    const float* b_v  = (const float*)d_in[8];
    const float* wfc  = (const float*)d_in[9];
    const float* b_fc = (const float*)d_in[10];
    const float* gamma= (const float*)d_in[11];
    const float* beta = (const float*)d_in[12];

    float* out0 = (float*)d_out;
    float* attn = (out_size >= 138412032) ? (out0 + (size_t)4194304) : nullptr;

    short* ws   = (short*)d_ws;
    short* qcb  = ws;                        // (B,L,1024) bf16 converted q
    short* kcb  = qcb + 4194304;
    short* vcb  = kcb + 4194304;
    short* wqb  = vcb + 4194304;             // (1024,1024) bf16 weights
    short* wkb  = wqb + 1048576;
    short* wvb  = wkb + 1048576;
    short* wfcb = wvb + 1048576;
    short* qhb  = wfcb + 1048576;            // (B,H,L,64)  [pre-scaled]
    short* khb  = qhb + 4194304;             // (B,H,T,64)
    short* vhTb = khb + 4194304;             // (B,H,64,T)
    short* Obf  = vhTb + 4194304;            // (B,L,H*64)
    short* ybf  = Obf + 4194304;             // (B,L,1024) pre-LN
    const size_t need = (size_t)(8 * 4194304 + 4 * 1048576) * 2;
    if (ws_size < need) return;

    cvt_k<<<dim3(2048, 7), 256, 0, stream>>>(
        qin, kin, vin, wq, wk, wv, wfc, qcb, kcb, vcb, wqb, wkb, wvb, wfcb);
    gemm_k<0><<<dim3(32, 8, 3), 256, 0, stream>>>(
        qcb, kcb, vcb, wqb, wkb, wvb, b_q, b_k, b_v, qhb, khb, vhTb,
        nullptr, nullptr);
    attn_fused<<<512, 512, 0, stream>>>(qhb, khb, vhTb, attn, Obf);
    gemm_k<1><<<dim3(64, 8), 256, 0, stream>>>(
        Obf, nullptr, nullptr, wfcb, nullptr, nullptr, b_fc, nullptr, nullptr,
        nullptr, nullptr, nullptr, qin, ybf);
    ln_k<<<1024, 256, 0, stream>>>(ybf, gamma, beta, out0);
}

// Round 21
// 262.650 us; speedup vs baseline: 1.0334x; 1.0334x over previous
//
#include <hip/hip_runtime.h>
#include <stdint.h>
#include <stddef.h>

// MHA + residual + LayerNorm. Inputs f32, outputs f32 (out0 + attn), internals bf16.
// B=2, L=T=2048, H=16, DK=DV=64, DM=1024   MI355X (gfx950)
// R21: exact restore of R19 (262.8us best). R20's exp2f/log2f folding regressed
//      (+8.6us): libm exp2f != native v_exp; __expf is already optimal.

typedef __attribute__((ext_vector_type(8))) short short8;
typedef __attribute__((ext_vector_type(4))) short short4v;
typedef __attribute__((ext_vector_type(4))) float f32x4;

#define MFMA16 __builtin_amdgcn_mfma_f32_16x16x32_bf16

__device__ __forceinline__ float bf2f(short s) {
    union { unsigned u; float f; } c; c.u = ((unsigned)(unsigned short)s) << 16; return c.f;
}
__device__ __forceinline__ unsigned short f2bf(float x) {
    union { float f; unsigned u; } c; c.f = x;
    unsigned r = (c.u + 0x7FFFu + ((c.u >> 16) & 1u)) >> 16;
    return (unsigned short)r;
}
__device__ __forceinline__ unsigned pk2(float a, float b) {
    return (unsigned)f2bf(a) | ((unsigned)f2bf(b) << 16);
}
__device__ __forceinline__ short8 ld8f(const float* p) {   // 8 f32 -> 8 bf16
    const f32x4 x = *(const f32x4*)p, y = *(const f32x4*)(p + 4);
    short8 r;
    r[0] = (short)f2bf(x[0]); r[1] = (short)f2bf(x[1]);
    r[2] = (short)f2bf(x[2]); r[3] = (short)f2bf(x[3]);
    r[4] = (short)f2bf(y[0]); r[5] = (short)f2bf(y[1]);
    r[6] = (short)f2bf(y[2]); r[7] = (short)f2bf(y[3]);
    return r;
}
// direct global->LDS 16B load; lands at lds_base + lane*16 (wave-uniform base)
__device__ __forceinline__ void gll16(const short* g, short* l) {
    __builtin_amdgcn_global_load_lds(
        (const __attribute__((address_space(1))) unsigned int*)g,
        (__attribute__((address_space(3))) unsigned int*)l,
        16, 0, 0);
}

// ---------------------------------------------------------------------------
// f32 -> bf16 bulk convert. blockIdx.y selects tensor.
// ---------------------------------------------------------------------------
__global__ __launch_bounds__(256)
void cvt_k(const float* __restrict__ s0, const float* __restrict__ s1,
           const float* __restrict__ s2, const float* __restrict__ s3,
           const float* __restrict__ s4, const float* __restrict__ s5,
           const float* __restrict__ s6,
           short* __restrict__ d0, short* __restrict__ d1, short* __restrict__ d2,
           short* __restrict__ d3, short* __restrict__ d4, short* __restrict__ d5,
           short* __restrict__ d6)
{
    const int t = blockIdx.y;
    const float* s; short* d; int n;
    switch (t) {
        case 0: s = s0; d = d0; n = 4194304; break;
        case 1: s = s1; d = d1; n = 4194304; break;
        case 2: s = s2; d = d2; n = 4194304; break;
        case 3: s = s3; d = d3; n = 1048576; break;
        case 4: s = s4; d = d4; n = 1048576; break;
        case 5: s = s5; d = d5; n = 1048576; break;
        default: s = s6; d = d6; n = 1048576; break;
    }
    const int idx = (blockIdx.x * 256 + threadIdx.x) * 8;
    if (idx < n) *(short8*)(d + idx) = ld8f(s + idx);
}

// ---------------------------------------------------------------------------
// m97-style GEMM with LDS-transpose coalesced epilogue.
// OP==0: BM=128, projections (z: 0=q [scaled 0.125], 1=k, 2=vT).
// OP==1: BM=64, fc + f32 resid -> bf16 row-major; grid (64,8)=512 blocks.
// ---------------------------------------------------------------------------
template<int OP>
__global__ __launch_bounds__(256)
void gemm_k(const short* __restrict__ A0, const short* __restrict__ A1, const short* __restrict__ A2,
            const short* __restrict__ W0, const short* __restrict__ W1, const short* __restrict__ W2,
            const float* __restrict__ bz0, const float* __restrict__ bz1, const float* __restrict__ bz2,
            short* __restrict__ D0, short* __restrict__ D1, short* __restrict__ D2,
            const float* __restrict__ resid, short* __restrict__ yout)
{
    constexpr int BM  = (OP == 1) ? 64 : 128;
    constexpr int ASH = BM * 32;                 // A-tile shorts
    constexpr int MTN = (OP == 1) ? 2 : 4;
    __shared__ short lds[2][ASH + 4096];         // A @0, W @ASH
    const int tid = threadIdx.x;
    const int lane = tid & 63, w = tid >> 6;
    const int rl = lane & 15, q = lane >> 4;
    const int m0 = blockIdx.x * BM, n0 = blockIdx.y * 128;
    const int wrow = (OP == 1) ? ((w >> 1) * 32) : ((w >> 1) * 64);
    const int wcol = (w & 1) * 64;

    const short *Ag, *Wg; const float* bias; short* dst; int zm;
    float oscale = 1.f;
    if (OP == 0) {
        const int z = blockIdx.z;
        Ag  = (z == 0) ? A0 : (z == 1) ? A1 : A2;
        Wg  = (z == 0) ? W0 : (z == 1) ? W1 : W2;
        bias= (z == 0) ? bz0 : (z == 1) ? bz1 : bz2;
        dst = (z == 0) ? D0 : (z == 1) ? D1 : D2;
        zm  = (z == 2) ? 1 : 0;
        if (z == 0) oscale = 0.125f;             // fold 1/sqrt(dk) into q
    } else {
        Ag = A0; Wg = W0; bias = bz0; dst = yout; zm = 2;
    }

    f32x4 acc[MTN][4];
    #pragma unroll
    for (int a = 0; a < MTN; ++a)
      #pragma unroll
      for (int b = 0; b < 4; ++b) acc[a][b] = (f32x4){0.f, 0.f, 0.f, 0.f};

    const int lr4 = lane >> 2;
    const int sc  = (lane & 3) * 8;

    auto stage = [&](int buf, int kt) {
        if (OP == 0) {
            gll16(Ag + (size_t)(m0 + (w*2+0)*16 + lr4) * 1024 + kt + sc, &lds[buf][(w*2+0)*512]);
            gll16(Ag + (size_t)(m0 + (w*2+1)*16 + lr4) * 1024 + kt + sc, &lds[buf][(w*2+1)*512]);
        } else {
            gll16(Ag + (size_t)(m0 + w*16 + lr4) * 1024 + kt + sc, &lds[buf][w*512]);
        }
        gll16(Wg + (size_t)(n0 + (w*2+0)*16 + lr4) * 1024 + kt + sc, &lds[buf][ASH+(w*2+0)*512]);
        gll16(Wg + (size_t)(n0 + (w*2+1)*16 + lr4) * 1024 + kt + sc, &lds[buf][ASH+(w*2+1)*512]);
    };

    stage(0, 0);
    __syncthreads();
    int cur = 0;
    for (int kt = 0; kt < 1024; kt += 32) {
        if (kt + 32 < 1024) { stage(cur ^ 1, kt + 32); }
        short8 af[MTN], bfv[4];
        #pragma unroll
        for (int mt = 0; mt < MTN; ++mt)
            af[mt] = *(const short8*)&lds[cur][(wrow + mt * 16 + rl) * 32 + q * 8];
        #pragma unroll
        for (int nt = 0; nt < 4; ++nt)
            bfv[nt] = *(const short8*)&lds[cur][ASH + (wcol + nt * 16 + rl) * 32 + q * 8];
        #pragma unroll
        for (int mt = 0; mt < MTN; ++mt)
          #pragma unroll
          for (int nt = 0; nt < 4; ++nt)
            acc[mt][nt] = MFMA16(af[mt], bfv[nt], acc[mt][nt], 0, 0, 0);
        __syncthreads();
        cur ^= 1;
    }

    float biasv[4];
    #pragma unroll
    for (int nt = 0; nt < 4; ++nt) biasv[nt] = bias[n0 + wcol + nt * 16 + rl];

    short* ldsF = &lds[0][0];          // epilogue scratch (64 x 136 shorts)

    if (zm == 0) {
        #pragma unroll
        for (int pass = 0; pass < 2; ++pass) {
            if ((w >> 1) == pass) {
                #pragma unroll
                for (int mt = 0; mt < 4; ++mt)
                  #pragma unroll
                  for (int nt = 0; nt < 4; ++nt) {
                    const int col = wcol + nt * 16 + rl;
                    #pragma unroll
                    for (int i = 0; i < 4; ++i)
                        ldsF[(mt * 16 + q * 4 + i) * 136 + col] =
                            (short)f2bf((acc[mt][nt][i] + biasv[nt]) * oscale);
                  }
            }
            __syncthreads();
            {
                const int hrun = tid >> 7, idx = tid & 127;
                const int lr = idx >> 1, ch = idx & 1;
                const int gm = m0 + pass * 64 + lr;
                const int bb = gm >> 11, ll = gm & 2047;
                const int h = (n0 + hrun * 64) >> 6;
                short* dstp = dst + (((size_t)(bb * 16 + h) * 2048) + ll) * 64 + ch * 32;
                const short* srcp = &ldsF[lr * 136 + hrun * 64 + ch * 32];
                #pragma unroll
                for (int c = 0; c < 4; ++c)
                    *(short8*)(dstp + c * 8) = *(const short8*)(srcp + c * 8);
            }
            __syncthreads();
        }
    } else if (zm == 1) {
        const int bb = m0 >> 11, t0 = m0 & 2047;
        #pragma unroll
        for (int pass = 0; pass < 2; ++pass) {
            if ((w & 1) == pass) {
                #pragma unroll
                for (int nt = 0; nt < 4; ++nt) {
                    const int lcol = nt * 16 + rl;
                    #pragma unroll
                    for (int mt = 0; mt < 4; ++mt) {
                        const int mloc = wrow + mt * 16 + q * 4;
                        const unsigned lo = pk2(acc[mt][nt][0] + biasv[nt],
                                                acc[mt][nt][1] + biasv[nt]);
                        const unsigned hi = pk2(acc[mt][nt][2] + biasv[nt],
                                                acc[mt][nt][3] + biasv[nt]);
                        *(unsigned long long*)&ldsF[lcol * 136 + mloc] =
                            (unsigned long long)lo | ((unsigned long long)hi << 32);
                    }
                }
            }
            __syncthreads();
            {
                const int lcol = tid >> 2, mch = tid & 3;
                const int gn = n0 + pass * 64 + lcol;
                const int h = gn >> 6, dv = gn & 63;
                short* dstp = dst + ((size_t)(bb * 16 + h) * 64 + dv) * 2048 + t0 + mch * 32;
                const short* srcp = &ldsF[lcol * 136 + mch * 32];
                #pragma unroll
                for (int c = 0; c < 4; ++c)
                    *(short8*)(dstp + c * 8) = *(const short8*)(srcp + c * 8);
            }
            __syncthreads();
        }
    } else {
        // fc, BM=64: single pass; all 4 waves fill 64x128 ldsF then store.
        #pragma unroll
        for (int mt = 0; mt < MTN; ++mt)
          #pragma unroll
          for (int nt = 0; nt < 4; ++nt) {
            const int col = wcol + nt * 16 + rl;
            #pragma unroll
            for (int i = 0; i < 4; ++i)
                ldsF[(wrow + mt * 16 + q * 4 + i) * 136 + col] =
                    (short)f2bf(acc[mt][nt][i] + biasv[nt]);
          }
        __syncthreads();
        {
            const int lr = tid >> 2, ch = tid & 3;
            const int gm = m0 + lr;
            const float* rp = resid + (size_t)gm * 1024 + n0 + ch * 32;
            short* dstp = dst + (size_t)gm * 1024 + n0 + ch * 32;
            const short* srcp = &ldsF[lr * 136 + ch * 32];
            #pragma unroll
            for (int c = 0; c < 4; ++c) {
                const short8 v = *(const short8*)(srcp + c * 8);
                const f32x4 r0 = *(const f32x4*)(rp + c * 8);
                const f32x4 r1 = *(const f32x4*)(rp + c * 8 + 4);
                short8 o;
                #pragma unroll
                for (int j = 0; j < 4; ++j) {
                    o[j]     = (short)f2bf(bf2f(v[j])     + r0[j]);
                    o[4 + j] = (short)f2bf(bf2f(v[4 + j]) + r1[j]);
                }
                *(short8*)(dstp + c * 8) = o;
            }
        }
    }
}

// ---------------------------------------------------------------------------
// XCD swizzle for the 512-block attention grid.
// ---------------------------------------------------------------------------
__device__ __forceinline__ void attn_swz(int j, int& rb, int& bh) {
    const int xcd = j & 7, k2 = j >> 3;
    rb = k2 & 15;
    bh = (xcd << 2) | (k2 >> 4);
}

// ---------------------------------------------------------------------------
// FUSED attention, 8 waves (512 thr), 128 q-rows per block. (R15 structure;
// q pre-scaled by 0.125 => p = __expf(st - 12).)
// ---------------------------------------------------------------------------
__global__ __launch_bounds__(512)
void attn_fused(const short* __restrict__ qh, const short* __restrict__ kh,
                const short* __restrict__ vhT,
                float* __restrict__ attn, short* __restrict__ Obf)
{
    __shared__ short ldsK[128 * 72];
    __shared__ short ldsV[64 * 136];
    __shared__ short ldsP[8][16 * 72];    // per-wave P half-tile: 16 r x 64 t (+pad)
    const int tid = threadIdx.x, lane = tid & 63, w = tid >> 6;   // w 0..7
    const int rl = lane & 15, q = lane >> 4;
    int rb, bh; attn_swz(blockIdx.x, rb, bh);
    const int r = rb * 128 + w * 16 + rl;
    const int b = bh >> 4, h = bh & 15;

    const size_t qoff = ((size_t)bh * 2048 + r) * 64;
    const short8 bq0 = *(const short8*)(qh + qoff + q * 8);
    const short8 bq1 = *(const short8*)(qh + qoff + 32 + q * 8);

    const size_t kbase = (size_t)bh * 2048 * 64;
    const size_t vbase = (size_t)bh * 64 * 2048;
    const int srow = tid >> 2, soff = (tid & 3) * 16;   // K staging: 128 rows, 32B/thr
    const int vrow = tid >> 3, voff = (tid & 7) * 16;   // V staging: 64 rows, 32B/thr
    const size_t abaseW = (((size_t)b * 2048 + rb * 128 + w * 16) * 16 + h) * 2048;

    // ---------------- phase 1: row sum ----------------
    float ls0 = 0.f, ls1 = 0.f, ls2 = 0.f, ls3 = 0.f;
    short8 kst[2], vst[2];
    {
        const short* src = kh + kbase + (size_t)srow * 64 + soff;
        kst[0] = *(const short8*)src;
        kst[1] = *(const short8*)(src + 8);
    }
    for (int it = 0; it < 16; ++it) {
        __syncthreads();
        *(short8*)&ldsK[srow * 72 + soff]     = kst[0];
        *(short8*)&ldsK[srow * 72 + soff + 8] = kst[1];
        __syncthreads();
        if (it < 15) {
            const short* src = kh + kbase + (size_t)(((it + 1) << 7) + srow) * 64 + soff;
            kst[0] = *(const short8*)src;
            kst[1] = *(const short8*)(src + 8);
        }
        #pragma unroll
        for (int tt = 0; tt < 8; ++tt) {
            const short* kr = &ldsK[(tt * 16 + rl) * 72];
            const short8 ak0 = *(const short8*)(kr + q * 8);
            const short8 ak1 = *(const short8*)(kr + 32 + q * 8);
            f32x4 st = MFMA16(ak0, bq0, (f32x4){0.f, 0.f, 0.f, 0.f}, 0, 0, 0);
            st = MFMA16(ak1, bq1, st, 0, 0, 0);
            ls0 += __expf(st[0] - 12.f);
            ls1 += __expf(st[1] - 12.f);
            ls2 += __expf(st[2] - 12.f);
            ls3 += __expf(st[3] - 12.f);
        }
    }
    float ls = (ls0 + ls1) + (ls2 + ls3);
    ls += __shfl_xor(ls, 16);
    ls += __shfl_xor(ls, 32);
    const float linv = 1.f / ls;

    // ---------------- phase 2: P write + PV ----------------
    f32x4 acc[4];
    #pragma unroll
    for (int dt = 0; dt < 4; ++dt) acc[dt] = (f32x4){0.f, 0.f, 0.f, 0.f};

    {
        const short* ks = kh + kbase + (size_t)srow * 64 + soff;
        const short* vs = vhT + vbase + (size_t)vrow * 2048 + voff;
        kst[0] = *(const short8*)ks;  kst[1] = *(const short8*)(ks + 8);
        vst[0] = *(const short8*)vs;  vst[1] = *(const short8*)(vs + 8);
    }
    for (int it = 0; it < 16; ++it) {
        const int t0 = it << 7;
        __syncthreads();
        *(short8*)&ldsK[srow * 72 + soff]      = kst[0];
        *(short8*)&ldsK[srow * 72 + soff + 8]  = kst[1];
        *(short8*)&ldsV[vrow * 136 + voff]     = vst[0];
        *(short8*)&ldsV[vrow * 136 + voff + 8] = vst[1];
        __syncthreads();
        if (it < 15) {
            const short* ks = kh + kbase + (size_t)(t0 + 128 + srow) * 64 + soff;
            const short* vs = vhT + vbase + (size_t)vrow * 2048 + t0 + 128 + voff;
            kst[0] = *(const short8*)ks;  kst[1] = *(const short8*)(ks + 8);
            vst[0] = *(const short8*)vs;  vst[1] = *(const short8*)(vs + 8);
        }
        #pragma unroll
        for (int hh = 0; hh < 4; ++hh) {
            float pv[8];
            #pragma unroll
            for (int sub = 0; sub < 2; ++sub) {
                const int tt = hh * 2 + sub;
                const short* kr = &ldsK[(tt * 16 + rl) * 72];
                const short8 ak0 = *(const short8*)(kr + q * 8);
                const short8 ak1 = *(const short8*)(kr + 32 + q * 8);
                f32x4 st = MFMA16(ak0, bq0, (f32x4){0.f, 0.f, 0.f, 0.f}, 0, 0, 0);
                st = MFMA16(ak1, bq1, st, 0, 0, 0);
                #pragma unroll
                for (int i = 0; i < 4; ++i)
                    pv[sub * 4 + i] = __expf(st[i] - 12.f) * linv;
            }
            short8 pb;
            #pragma unroll
            for (int j = 0; j < 8; ++j) pb[j] = (short)f2bf(pv[j]);
            {
                const int lc = (hh & 1) * 32;
                short4v plo, phi;
                plo[0] = pb[0]; plo[1] = pb[1]; plo[2] = pb[2]; plo[3] = pb[3];
                phi[0] = pb[4]; phi[1] = pb[5]; phi[2] = pb[6]; phi[3] = pb[7];
                *(short4v*)&ldsP[w][rl * 72 + lc + q * 4] = plo;
                *(short4v*)&ldsP[w][rl * 72 + lc + 16 + q * 4] = phi;
            }
            #pragma unroll
            for (int dt = 0; dt < 4; ++dt) {
                const short* vr = &ldsV[(dt * 16 + rl) * 136 + hh * 32];
                const short4v vlo = *(const short4v*)(vr + q * 4);
                const short4v vhi = *(const short4v*)(vr + 16 + q * 4);
                short8 va;
                va[0] = vlo[0]; va[1] = vlo[1]; va[2] = vlo[2]; va[3] = vlo[3];
                va[4] = vhi[0]; va[5] = vhi[1]; va[6] = vhi[2]; va[7] = vhi[3];
                acc[dt] = MFMA16(va, pb, acc[dt], 0, 0, 0);
            }
            if ((hh & 1) && attn != nullptr) {
                const int hcol = hh >> 1;
                const int c8 = (lane & 7) * 8;
                #pragma unroll
                for (int pass = 0; pass < 2; ++pass) {
                    const int rloc = pass * 8 + (lane >> 3);
                    const short8 p8 = *(const short8*)&ldsP[w][rloc * 72 + c8];
                    float* dstp = attn + abaseW + (size_t)rloc * 32768 + t0 + hcol * 64 + c8;
                    f32x4 o0, o1;
                    #pragma unroll
                    for (int j = 0; j < 4; ++j) {
                        o0[j] = bf2f(p8[j]);
                        o1[j] = bf2f(p8[4 + j]);
                    }
                    *(f32x4*)dstp = o0;
                    *(f32x4*)(dstp + 4) = o1;
                }
            }
        }
    }

    #pragma unroll
    for (int dt = 0; dt < 4; ++dt) {
        const int dv0 = dt * 16 + q * 4;
        const unsigned lo = pk2(acc[dt][0], acc[dt][1]);
        const unsigned hi = pk2(acc[dt][2], acc[dt][3]);
        const size_t oidx = ((size_t)b * 2048 + r) * 1024 + h * 64 + dv0;
        *(unsigned long long*)&Obf[oidx] =
            (unsigned long long)lo | ((unsigned long long)hi << 32);
    }
}

// ---------------------------------------------------------------------------
// Rowwise LayerNorm. ybf bf16 in, out f32.
// ---------------------------------------------------------------------------
__global__ __launch_bounds__(256)
void ln_k(const short* __restrict__ ybf, const float* __restrict__ gamma,
          const float* __restrict__ beta, float* __restrict__ out)
{
    const int tid = threadIdx.x, lane = tid & 63, w = tid >> 6;
    const int row = blockIdx.x * 4 + w;
    const short* yr = ybf + (size_t)row * 1024 + lane * 16;
    const short8 v0 = *(const short8*)(yr);
    const short8 v1 = *(const short8*)(yr + 8);
    float x[16];
    #pragma unroll
    for (int j = 0; j < 8; ++j) { x[j] = bf2f(v0[j]); x[8 + j] = bf2f(v1[j]); }
    float s = 0.f, s2 = 0.f;
    #pragma unroll
    for (int j = 0; j < 16; ++j) { s += x[j]; s2 += x[j] * x[j]; }
    #pragma unroll
    for (int off = 1; off < 64; off <<= 1) {
        s  += __shfl_xor(s, off);
        s2 += __shfl_xor(s2, off);
    }
    const float mean = s * (1.f / 1024.f);
    const float var  = s2 * (1.f / 1024.f) - mean * mean;
    const float rs   = rsqrtf(var + 1e-5f);
    float* orow = out + (size_t)row * 1024 + lane * 16;
    #pragma unroll
    for (int j4 = 0; j4 < 4; ++j4) {
        f32x4 o;
        #pragma unroll
        for (int e = 0; e < 4; ++e) {
            const int c = lane * 16 + j4 * 4 + e;
            o[e] = (x[j4 * 4 + e] - mean) * rs * gamma[c] + beta[c];
        }
        *(f32x4*)(orow + j4 * 4) = o;
    }
}

// ---------------------------------------------------------------------------
extern "C" void kernel_launch(void* const* d_in, const int* in_sizes, int n_in,
                              void* d_out, int out_size, void* d_ws, size_t ws_size,
                              hipStream_t stream)
{
    (void)in_sizes; (void)n_in;
    const float* qin  = (const float*)d_in[0];
    const float* kin  = (const float*)d_in[1];
    const float* vin  = (const float*)d_in[2];
    const float* wq   = (const float*)d_in[3];
    const float* b_q  = (const float*)d_in[4];
    const float* wk   = (const float*)d_in[5];
    const float* b_k  = (const float*)d_in[6];
    const float* wv   = (const float*)d_in[7];
    const float* b_v  = (const float*)d_in[8];
    const float* wfc  = (const float*)d_in[9];
    const float* b_fc = (const float*)d_in[10];
    const float* gamma= (const float*)d_in[11];
    const float* beta = (const float*)d_in[12];

    float* out0 = (float*)d_out;
    float* attn = (out_size >= 138412032) ? (out0 + (size_t)4194304) : nullptr;

    short* ws   = (short*)d_ws;
    short* qcb  = ws;                        // (B,L,1024) bf16 converted q
    short* kcb  = qcb + 4194304;
    short* vcb  = kcb + 4194304;
    short* wqb  = vcb + 4194304;             // (1024,1024) bf16 weights
    short* wkb  = wqb + 1048576;
    short* wvb  = wkb + 1048576;
    short* wfcb = wvb + 1048576;
    short* qhb  = wfcb + 1048576;            // (B,H,L,64)  [pre-scaled by 0.125]
    short* khb  = qhb + 4194304;             // (B,H,T,64)
    short* vhTb = khb + 4194304;             // (B,H,64,T)
    short* Obf  = vhTb + 4194304;            // (B,L,H*64)
    short* ybf  = Obf + 4194304;             // (B,L,1024) pre-LN
    const size_t need = (size_t)(8 * 4194304 + 4 * 1048576) * 2;
    if (ws_size < need) return;

    cvt_k<<<dim3(2048, 7), 256, 0, stream>>>(
        qin, kin, vin, wq, wk, wv, wfc, qcb, kcb, vcb, wqb, wkb, wvb, wfcb);
    gemm_k<0><<<dim3(32, 8, 3), 256, 0, stream>>>(
        qcb, kcb, vcb, wqb, wkb, wvb, b_q, b_k, b_v, qhb, khb, vhTb,
        nullptr, nullptr);
    attn_fused<<<512, 512, 0, stream>>>(qhb, khb, vhTb, attn, Obf);
    gemm_k<1><<<dim3(64, 8), 256, 0, stream>>>(
        Obf, nullptr, nullptr, wfcb, nullptr, nullptr, b_fc, nullptr, nullptr,
        nullptr, nullptr, nullptr, qin, ybf);
    ln_k<<<1024, 256, 0, stream>>>(ybf, gamma, beta, out0);
}

// Round 22
// 261.829 us; speedup vs baseline: 1.0367x; 1.0031x over previous
//
#include <hip/hip_runtime.h>
#include <stdint.h>
#include <stddef.h>

// MHA + residual + LayerNorm. Inputs f32, outputs f32 (out0 + attn), internals bf16.
// B=2, L=T=2048, H=16, DK=DV=64, DM=1024   MI355X (gfx950)
// R22 (from R19/R21 anchor 262.6us): attn barriers use lgkmcnt-only drain
//      (s_waitcnt lgkmcnt(0) + s_barrier) instead of __syncthreads' full
//      vmcnt(0) drain -> the 537MB attn stores become fire-and-forget instead
//      of being retired at each of the 64 barriers/block (T4 mechanism).
//      gemm/cvt/LN byte-identical to R21.

typedef __attribute__((ext_vector_type(8))) short short8;
typedef __attribute__((ext_vector_type(4))) short short4v;
typedef __attribute__((ext_vector_type(4))) float f32x4;

#define MFMA16 __builtin_amdgcn_mfma_f32_16x16x32_bf16

__device__ __forceinline__ float bf2f(short s) {
    union { unsigned u; float f; } c; c.u = ((unsigned)(unsigned short)s) << 16; return c.f;
}
__device__ __forceinline__ unsigned short f2bf(float x) {
    union { float f; unsigned u; } c; c.f = x;
    unsigned r = (c.u + 0x7FFFu + ((c.u >> 16) & 1u)) >> 16;
    return (unsigned short)r;
}
__device__ __forceinline__ unsigned pk2(float a, float b) {
    return (unsigned)f2bf(a) | ((unsigned)f2bf(b) << 16);
}
__device__ __forceinline__ short8 ld8f(const float* p) {   // 8 f32 -> 8 bf16
    const f32x4 x = *(const f32x4*)p, y = *(const f32x4*)(p + 4);
    short8 r;
    r[0] = (short)f2bf(x[0]); r[1] = (short)f2bf(x[1]);
    r[2] = (short)f2bf(x[2]); r[3] = (short)f2bf(x[3]);
    r[4] = (short)f2bf(y[0]); r[5] = (short)f2bf(y[1]);
    r[6] = (short)f2bf(y[2]); r[7] = (short)f2bf(y[3]);
    return r;
}
// direct global->LDS 16B load; lands at lds_base + lane*16 (wave-uniform base)
__device__ __forceinline__ void gll16(const short* g, short* l) {
    __builtin_amdgcn_global_load_lds(
        (const __attribute__((address_space(1))) unsigned int*)g,
        (__attribute__((address_space(3))) unsigned int*)l,
        16, 0, 0);
}
// barrier with LDS-only drain: global stores stay in flight (T4).
__device__ __forceinline__ void bar_lgkm() {
    asm volatile("s_waitcnt lgkmcnt(0)" ::: "memory");
    __builtin_amdgcn_s_barrier();
}

// ---------------------------------------------------------------------------
// f32 -> bf16 bulk convert. blockIdx.y selects tensor. (unchanged)
// ---------------------------------------------------------------------------
__global__ __launch_bounds__(256)
void cvt_k(const float* __restrict__ s0, const float* __restrict__ s1,
           const float* __restrict__ s2, const float* __restrict__ s3,
           const float* __restrict__ s4, const float* __restrict__ s5,
           const float* __restrict__ s6,
           short* __restrict__ d0, short* __restrict__ d1, short* __restrict__ d2,
           short* __restrict__ d3, short* __restrict__ d4, short* __restrict__ d5,
           short* __restrict__ d6)
{
    const int t = blockIdx.y;
    const float* s; short* d; int n;
    switch (t) {
        case 0: s = s0; d = d0; n = 4194304; break;
        case 1: s = s1; d = d1; n = 4194304; break;
        case 2: s = s2; d = d2; n = 4194304; break;
        case 3: s = s3; d = d3; n = 1048576; break;
        case 4: s = s4; d = d4; n = 1048576; break;
        case 5: s = s5; d = d5; n = 1048576; break;
        default: s = s6; d = d6; n = 1048576; break;
    }
    const int idx = (blockIdx.x * 256 + threadIdx.x) * 8;
    if (idx < n) *(short8*)(d + idx) = ld8f(s + idx);
}

// ---------------------------------------------------------------------------
// m97-style GEMM with LDS-transpose coalesced epilogue. (unchanged from R19/R21)
// OP==0: BM=128, projections (z: 0=q [scaled 0.125], 1=k, 2=vT).
// OP==1: BM=64, fc + f32 resid -> bf16 row-major; grid (64,8)=512 blocks.
// ---------------------------------------------------------------------------
template<int OP>
__global__ __launch_bounds__(256)
void gemm_k(const short* __restrict__ A0, const short* __restrict__ A1, const short* __restrict__ A2,
            const short* __restrict__ W0, const short* __restrict__ W1, const short* __restrict__ W2,
            const float* __restrict__ bz0, const float* __restrict__ bz1, const float* __restrict__ bz2,
            short* __restrict__ D0, short* __restrict__ D1, short* __restrict__ D2,
            const float* __restrict__ resid, short* __restrict__ yout)
{
    constexpr int BM  = (OP == 1) ? 64 : 128;
    constexpr int ASH = BM * 32;                 // A-tile shorts
    constexpr int MTN = (OP == 1) ? 2 : 4;
    __shared__ short lds[2][ASH + 4096];         // A @0, W @ASH
    const int tid = threadIdx.x;
    const int lane = tid & 63, w = tid >> 6;
    const int rl = lane & 15, q = lane >> 4;
    const int m0 = blockIdx.x * BM, n0 = blockIdx.y * 128;
    const int wrow = (OP == 1) ? ((w >> 1) * 32) : ((w >> 1) * 64);
    const int wcol = (w & 1) * 64;

    const short *Ag, *Wg; const float* bias; short* dst; int zm;
    float oscale = 1.f;
    if (OP == 0) {
        const int z = blockIdx.z;
        Ag  = (z == 0) ? A0 : (z == 1) ? A1 : A2;
        Wg  = (z == 0) ? W0 : (z == 1) ? W1 : W2;
        bias= (z == 0) ? bz0 : (z == 1) ? bz1 : bz2;
        dst = (z == 0) ? D0 : (z == 1) ? D1 : D2;
        zm  = (z == 2) ? 1 : 0;
        if (z == 0) oscale = 0.125f;             // fold 1/sqrt(dk) into q
    } else {
        Ag = A0; Wg = W0; bias = bz0; dst = yout; zm = 2;
    }

    f32x4 acc[MTN][4];
    #pragma unroll
    for (int a = 0; a < MTN; ++a)
      #pragma unroll
      for (int b = 0; b < 4; ++b) acc[a][b] = (f32x4){0.f, 0.f, 0.f, 0.f};

    const int lr4 = lane >> 2;
    const int sc  = (lane & 3) * 8;

    auto stage = [&](int buf, int kt) {
        if (OP == 0) {
            gll16(Ag + (size_t)(m0 + (w*2+0)*16 + lr4) * 1024 + kt + sc, &lds[buf][(w*2+0)*512]);
            gll16(Ag + (size_t)(m0 + (w*2+1)*16 + lr4) * 1024 + kt + sc, &lds[buf][(w*2+1)*512]);
        } else {
            gll16(Ag + (size_t)(m0 + w*16 + lr4) * 1024 + kt + sc, &lds[buf][w*512]);
        }
        gll16(Wg + (size_t)(n0 + (w*2+0)*16 + lr4) * 1024 + kt + sc, &lds[buf][ASH+(w*2+0)*512]);
        gll16(Wg + (size_t)(n0 + (w*2+1)*16 + lr4) * 1024 + kt + sc, &lds[buf][ASH+(w*2+1)*512]);
    };

    stage(0, 0);
    __syncthreads();
    int cur = 0;
    for (int kt = 0; kt < 1024; kt += 32) {
        if (kt + 32 < 1024) { stage(cur ^ 1, kt + 32); }
        short8 af[MTN], bfv[4];
        #pragma unroll
        for (int mt = 0; mt < MTN; ++mt)
            af[mt] = *(const short8*)&lds[cur][(wrow + mt * 16 + rl) * 32 + q * 8];
        #pragma unroll
        for (int nt = 0; nt < 4; ++nt)
            bfv[nt] = *(const short8*)&lds[cur][ASH + (wcol + nt * 16 + rl) * 32 + q * 8];
        #pragma unroll
        for (int mt = 0; mt < MTN; ++mt)
          #pragma unroll
          for (int nt = 0; nt < 4; ++nt)
            acc[mt][nt] = MFMA16(af[mt], bfv[nt], acc[mt][nt], 0, 0, 0);
        __syncthreads();
        cur ^= 1;
    }

    float biasv[4];
    #pragma unroll
    for (int nt = 0; nt < 4; ++nt) biasv[nt] = bias[n0 + wcol + nt * 16 + rl];

    short* ldsF = &lds[0][0];          // epilogue scratch (64 x 136 shorts)

    if (zm == 0) {
        #pragma unroll
        for (int pass = 0; pass < 2; ++pass) {
            if ((w >> 1) == pass) {
                #pragma unroll
                for (int mt = 0; mt < 4; ++mt)
                  #pragma unroll
                  for (int nt = 0; nt < 4; ++nt) {
                    const int col = wcol + nt * 16 + rl;
                    #pragma unroll
                    for (int i = 0; i < 4; ++i)
                        ldsF[(mt * 16 + q * 4 + i) * 136 + col] =
                            (short)f2bf((acc[mt][nt][i] + biasv[nt]) * oscale);
                  }
            }
            __syncthreads();
            {
                const int hrun = tid >> 7, idx = tid & 127;
                const int lr = idx >> 1, ch = idx & 1;
                const int gm = m0 + pass * 64 + lr;
                const int bb = gm >> 11, ll = gm & 2047;
                const int h = (n0 + hrun * 64) >> 6;
                short* dstp = dst + (((size_t)(bb * 16 + h) * 2048) + ll) * 64 + ch * 32;
                const short* srcp = &ldsF[lr * 136 + hrun * 64 + ch * 32];
                #pragma unroll
                for (int c = 0; c < 4; ++c)
                    *(short8*)(dstp + c * 8) = *(const short8*)(srcp + c * 8);
            }
            __syncthreads();
        }
    } else if (zm == 1) {
        const int bb = m0 >> 11, t0 = m0 & 2047;
        #pragma unroll
        for (int pass = 0; pass < 2; ++pass) {
            if ((w & 1) == pass) {
                #pragma unroll
                for (int nt = 0; nt < 4; ++nt) {
                    const int lcol = nt * 16 + rl;
                    #pragma unroll
                    for (int mt = 0; mt < 4; ++mt) {
                        const int mloc = wrow + mt * 16 + q * 4;
                        const unsigned lo = pk2(acc[mt][nt][0] + biasv[nt],
                                                acc[mt][nt][1] + biasv[nt]);
                        const unsigned hi = pk2(acc[mt][nt][2] + biasv[nt],
                                                acc[mt][nt][3] + biasv[nt]);
                        *(unsigned long long*)&ldsF[lcol * 136 + mloc] =
                            (unsigned long long)lo | ((unsigned long long)hi << 32);
                    }
                }
            }
            __syncthreads();
            {
                const int lcol = tid >> 2, mch = tid & 3;
                const int gn = n0 + pass * 64 + lcol;
                const int h = gn >> 6, dv = gn & 63;
                short* dstp = dst + ((size_t)(bb * 16 + h) * 64 + dv) * 2048 + t0 + mch * 32;
                const short* srcp = &ldsF[lcol * 136 + mch * 32];
                #pragma unroll
                for (int c = 0; c < 4; ++c)
                    *(short8*)(dstp + c * 8) = *(const short8*)(srcp + c * 8);
            }
            __syncthreads();
        }
    } else {
        // fc, BM=64: single pass; all 4 waves fill 64x128 ldsF then store.
        #pragma unroll
        for (int mt = 0; mt < MTN; ++mt)
          #pragma unroll
          for (int nt = 0; nt < 4; ++nt) {
            const int col = wcol + nt * 16 + rl;
            #pragma unroll
            for (int i = 0; i < 4; ++i)
                ldsF[(wrow + mt * 16 + q * 4 + i) * 136 + col] =
                    (short)f2bf(acc[mt][nt][i] + biasv[nt]);
          }
        __syncthreads();
        {
            const int lr = tid >> 2, ch = tid & 3;
            const int gm = m0 + lr;
            const float* rp = resid + (size_t)gm * 1024 + n0 + ch * 32;
            short* dstp = dst + (size_t)gm * 1024 + n0 + ch * 32;
            const short* srcp = &ldsF[lr * 136 + ch * 32];
            #pragma unroll
            for (int c = 0; c < 4; ++c) {
                const short8 v = *(const short8*)(srcp + c * 8);
                const f32x4 r0 = *(const f32x4*)(rp + c * 8);
                const f32x4 r1 = *(const f32x4*)(rp + c * 8 + 4);
                short8 o;
                #pragma unroll
                for (int j = 0; j < 4; ++j) {
                    o[j]     = (short)f2bf(bf2f(v[j])     + r0[j]);
                    o[4 + j] = (short)f2bf(bf2f(v[4 + j]) + r1[j]);
                }
                *(short8*)(dstp + c * 8) = o;
            }
        }
    }
}

// ---------------------------------------------------------------------------
// XCD swizzle for the 512-block attention grid.
// ---------------------------------------------------------------------------
__device__ __forceinline__ void attn_swz(int j, int& rb, int& bh) {
    const int xcd = j & 7, k2 = j >> 3;
    rb = k2 & 15;
    bh = (xcd << 2) | (k2 >> 4);
}

// ---------------------------------------------------------------------------
// FUSED attention, 8 waves (512 thr), 128 q-rows per block. R21 structure, but
// all loop barriers are lgkm-only (bar_lgkm): attn stores fire-and-forget.
// ---------------------------------------------------------------------------
__global__ __launch_bounds__(512)
void attn_fused(const short* __restrict__ qh, const short* __restrict__ kh,
                const short* __restrict__ vhT,
                float* __restrict__ attn, short* __restrict__ Obf)
{
    __shared__ short ldsK[128 * 72];
    __shared__ short ldsV[64 * 136];
    __shared__ short ldsP[8][16 * 72];    // per-wave P half-tile: 16 r x 64 t (+pad)
    const int tid = threadIdx.x, lane = tid & 63, w = tid >> 6;   // w 0..7
    const int rl = lane & 15, q = lane >> 4;
    int rb, bh; attn_swz(blockIdx.x, rb, bh);
    const int r = rb * 128 + w * 16 + rl;
    const int b = bh >> 4, h = bh & 15;

    const size_t qoff = ((size_t)bh * 2048 + r) * 64;
    const short8 bq0 = *(const short8*)(qh + qoff + q * 8);
    const short8 bq1 = *(const short8*)(qh + qoff + 32 + q * 8);

    const size_t kbase = (size_t)bh * 2048 * 64;
    const size_t vbase = (size_t)bh * 64 * 2048;
    const int srow = tid >> 2, soff = (tid & 3) * 16;   // K staging: 128 rows, 32B/thr
    const int vrow = tid >> 3, voff = (tid & 7) * 16;   // V staging: 64 rows, 32B/thr
    const size_t abaseW = (((size_t)b * 2048 + rb * 128 + w * 16) * 16 + h) * 2048;

    // ---------------- phase 1: row sum ----------------
    float ls0 = 0.f, ls1 = 0.f, ls2 = 0.f, ls3 = 0.f;
    short8 kst[2], vst[2];
    {
        const short* src = kh + kbase + (size_t)srow * 64 + soff;
        kst[0] = *(const short8*)src;
        kst[1] = *(const short8*)(src + 8);
    }
    for (int it = 0; it < 16; ++it) {
        bar_lgkm();
        *(short8*)&ldsK[srow * 72 + soff]     = kst[0];
        *(short8*)&ldsK[srow * 72 + soff + 8] = kst[1];
        bar_lgkm();
        if (it < 15) {
            const short* src = kh + kbase + (size_t)(((it + 1) << 7) + srow) * 64 + soff;
            kst[0] = *(const short8*)src;
            kst[1] = *(const short8*)(src + 8);
        }
        #pragma unroll
        for (int tt = 0; tt < 8; ++tt) {
            const short* kr = &ldsK[(tt * 16 + rl) * 72];
            const short8 ak0 = *(const short8*)(kr + q * 8);
            const short8 ak1 = *(const short8*)(kr + 32 + q * 8);
            f32x4 st = MFMA16(ak0, bq0, (f32x4){0.f, 0.f, 0.f, 0.f}, 0, 0, 0);
            st = MFMA16(ak1, bq1, st, 0, 0, 0);
            ls0 += __expf(st[0] - 12.f);
            ls1 += __expf(st[1] - 12.f);
            ls2 += __expf(st[2] - 12.f);
            ls3 += __expf(st[3] - 12.f);
        }
    }
    float ls = (ls0 + ls1) + (ls2 + ls3);
    ls += __shfl_xor(ls, 16);
    ls += __shfl_xor(ls, 32);
    const float linv = 1.f / ls;

    // ---------------- phase 2: P write + PV ----------------
    f32x4 acc[4];
    #pragma unroll
    for (int dt = 0; dt < 4; ++dt) acc[dt] = (f32x4){0.f, 0.f, 0.f, 0.f};

    {
        const short* ks = kh + kbase + (size_t)srow * 64 + soff;
        const short* vs = vhT + vbase + (size_t)vrow * 2048 + voff;
        kst[0] = *(const short8*)ks;  kst[1] = *(const short8*)(ks + 8);
        vst[0] = *(const short8*)vs;  vst[1] = *(const short8*)(vs + 8);
    }
    for (int it = 0; it < 16; ++it) {
        const int t0 = it << 7;
        bar_lgkm();
        *(short8*)&ldsK[srow * 72 + soff]      = kst[0];
        *(short8*)&ldsK[srow * 72 + soff + 8]  = kst[1];
        *(short8*)&ldsV[vrow * 136 + voff]     = vst[0];
        *(short8*)&ldsV[vrow * 136 + voff + 8] = vst[1];
        bar_lgkm();
        if (it < 15) {
            const short* ks = kh + kbase + (size_t)(t0 + 128 + srow) * 64 + soff;
            const short* vs = vhT + vbase + (size_t)vrow * 2048 + t0 + 128 + voff;
            kst[0] = *(const short8*)ks;  kst[1] = *(const short8*)(ks + 8);
            vst[0] = *(const short8*)vs;  vst[1] = *(const short8*)(vs + 8);
        }
        #pragma unroll
        for (int hh = 0; hh < 4; ++hh) {
            float pv[8];
            #pragma unroll
            for (int sub = 0; sub < 2; ++sub) {
                const int tt = hh * 2 + sub;
                const short* kr = &ldsK[(tt * 16 + rl) * 72];
                const short8 ak0 = *(const short8*)(kr + q * 8);
                const short8 ak1 = *(const short8*)(kr + 32 + q * 8);
                f32x4 st = MFMA16(ak0, bq0, (f32x4){0.f, 0.f, 0.f, 0.f}, 0, 0, 0);
                st = MFMA16(ak1, bq1, st, 0, 0, 0);
                #pragma unroll
                for (int i = 0; i < 4; ++i)
                    pv[sub * 4 + i] = __expf(st[i] - 12.f) * linv;
            }
            short8 pb;
            #pragma unroll
            for (int j = 0; j < 8; ++j) pb[j] = (short)f2bf(pv[j]);
            {
                const int lc = (hh & 1) * 32;
                short4v plo, phi;
                plo[0] = pb[0]; plo[1] = pb[1]; plo[2] = pb[2]; plo[3] = pb[3];
                phi[0] = pb[4]; phi[1] = pb[5]; phi[2] = pb[6]; phi[3] = pb[7];
                *(short4v*)&ldsP[w][rl * 72 + lc + q * 4] = plo;
                *(short4v*)&ldsP[w][rl * 72 + lc + 16 + q * 4] = phi;
            }
            #pragma unroll
            for (int dt = 0; dt < 4; ++dt) {
                const short* vr = &ldsV[(dt * 16 + rl) * 136 + hh * 32];
                const short4v vlo = *(const short4v*)(vr + q * 4);
                const short4v vhi = *(const short4v*)(vr + 16 + q * 4);
                short8 va;
                va[0] = vlo[0]; va[1] = vlo[1]; va[2] = vlo[2]; va[3] = vlo[3];
                va[4] = vhi[0]; va[5] = vhi[1]; va[6] = vhi[2]; va[7] = vhi[3];
                acc[dt] = MFMA16(va, pb, acc[dt], 0, 0, 0);
            }
            if ((hh & 1) && attn != nullptr) {
                const int hcol = hh >> 1;
                const int c8 = (lane & 7) * 8;
                #pragma unroll
                for (int pass = 0; pass < 2; ++pass) {
                    const int rloc = pass * 8 + (lane >> 3);
                    const short8 p8 = *(const short8*)&ldsP[w][rloc * 72 + c8];
                    float* dstp = attn + abaseW + (size_t)rloc * 32768 + t0 + hcol * 64 + c8;
                    f32x4 o0, o1;
                    #pragma unroll
                    for (int j = 0; j < 4; ++j) {
                        o0[j] = bf2f(p8[j]);
                        o1[j] = bf2f(p8[4 + j]);
                    }
                    *(f32x4*)dstp = o0;
                    *(f32x4*)(dstp + 4) = o1;
                }
            }
        }
    }

    #pragma unroll
    for (int dt = 0; dt < 4; ++dt) {
        const int dv0 = dt * 16 + q * 4;
        const unsigned lo = pk2(acc[dt][0], acc[dt][1]);
        const unsigned hi = pk2(acc[dt][2], acc[dt][3]);
        const size_t oidx = ((size_t)b * 2048 + r) * 1024 + h * 64 + dv0;
        *(unsigned long long*)&Obf[oidx] =
            (unsigned long long)lo | ((unsigned long long)hi << 32);
    }
}

// ---------------------------------------------------------------------------
// Rowwise LayerNorm. ybf bf16 in, out f32.
// ---------------------------------------------------------------------------
__global__ __launch_bounds__(256)
void ln_k(const short* __restrict__ ybf, const float* __restrict__ gamma,
          const float* __restrict__ beta, float* __restrict__ out)
{
    const int tid = threadIdx.x, lane = tid & 63, w = tid >> 6;
    const int row = blockIdx.x * 4 + w;
    const short* yr = ybf + (size_t)row * 1024 + lane * 16;
    const short8 v0 = *(const short8*)(yr);
    const short8 v1 = *(const short8*)(yr + 8);
    float x[16];
    #pragma unroll
    for (int j = 0; j < 8; ++j) { x[j] = bf2f(v0[j]); x[8 + j] = bf2f(v1[j]); }
    float s = 0.f, s2 = 0.f;
    #pragma unroll
    for (int j = 0; j < 16; ++j) { s += x[j]; s2 += x[j] * x[j]; }
    #pragma unroll
    for (int off = 1; off < 64; off <<= 1) {
        s  += __shfl_xor(s, off);
        s2 += __shfl_xor(s2, off);
    }
    const float mean = s * (1.f / 1024.f);
    const float var  = s2 * (1.f / 1024.f) - mean * mean;
    const float rs   = rsqrtf(var + 1e-5f);
    float* orow = out + (size_t)row * 1024 + lane * 16;
    #pragma unroll
    for (int j4 = 0; j4 < 4; ++j4) {
        f32x4 o;
        #pragma unroll
        for (int e = 0; e < 4; ++e) {
            const int c = lane * 16 + j4 * 4 + e;
            o[e] = (x[j4 * 4 + e] - mean) * rs * gamma[c] + beta[c];
        }
        *(f32x4*)(orow + j4 * 4) = o;
    }
}

// ---------------------------------------------------------------------------
extern "C" void kernel_launch(void* const* d_in, const int* in_sizes, int n_in,
                              void* d_out, int out_size, void* d_ws, size_t ws_size,
                              hipStream_t stream)
{
    (void)in_sizes; (void)n_in;
    const float* qin  = (const float*)d_in[0];
    const float* kin  = (const float*)d_in[1];
    const float* vin  = (const float*)d_in[2];
    const float* wq   = (const float*)d_in[3];
    const float* b_q  = (const float*)d_in[4];
    const float* wk   = (const float*)d_in[5];
    const float* b_k  = (const float*)d_in[6];
    const float* wv   = (const float*)d_in[7];
    const float* b_v  = (const float*)d_in[8];
    const float* wfc  = (const float*)d_in[9];
    const float* b_fc = (const float*)d_in[10];
    const float* gamma= (const float*)d_in[11];
    const float* beta = (const float*)d_in[12];

    float* out0 = (float*)d_out;
    float* attn = (out_size >= 138412032) ? (out0 + (size_t)4194304) : nullptr;

    short* ws   = (short*)d_ws;
    short* qcb  = ws;                        // (B,L,1024) bf16 converted q
    short* kcb  = qcb + 4194304;
    short* vcb  = kcb + 4194304;
    short* wqb  = vcb + 4194304;             // (1024,1024) bf16 weights
    short* wkb  = wqb + 1048576;
    short* wvb  = wkb + 1048576;
    short* wfcb = wvb + 1048576;
    short* qhb  = wfcb + 1048576;            // (B,H,L,64)  [pre-scaled by 0.125]
    short* khb  = qhb + 4194304;             // (B,H,T,64)
    short* vhTb = khb + 4194304;             // (B,H,64,T)
    short* Obf  = vhTb + 4194304;            // (B,L,H*64)
    short* ybf  = Obf + 4194304;             // (B,L,1024) pre-LN
    const size_t need = (size_t)(8 * 4194304 + 4 * 1048576) * 2;
    if (ws_size < need) return;

    cvt_k<<<dim3(2048, 7), 256, 0, stream>>>(
        qin, kin, vin, wq, wk, wv, wfc, qcb, kcb, vcb, wqb, wkb, wvb, wfcb);
    gemm_k<0><<<dim3(32, 8, 3), 256, 0, stream>>>(
        qcb, kcb, vcb, wqb, wkb, wvb, b_q, b_k, b_v, qhb, khb, vhTb,
        nullptr, nullptr);
    attn_fused<<<512, 512, 0, stream>>>(qhb, khb, vhTb, attn, Obf);
    gemm_k<1><<<dim3(64, 8), 256, 0, stream>>>(
        Obf, nullptr, nullptr, wfcb, nullptr, nullptr, b_fc, nullptr, nullptr,
        nullptr, nullptr, nullptr, qin, ybf);
    ln_k<<<1024, 256, 0, stream>>>(ybf, gamma, beta, out0);
}